// Round 6
// baseline (210.623 us; speedup 1.0000x reference)
//
#include <hip/hip_runtime.h>

#define LOG2E 1.4426950408889634f
#define LN2   0.6931471805599453

// B blocks x 128 threads. Wave 0: forward recursion t=0..m-1; wave 1: backward
// recursion t=len-1..m. Z = sum_k A_m[k]*B_m[k]. Lane k owns state k; the
// per-step 64-wide broadcast of the state vector is done with v_readlane
// (SGPR broadcast, VALU pipe) -- NO LDS in the serial loop. State u is
// unnormalized; each step divides by the PREVIOUS step's power-of-two scale
// (exact integer bookkeeping, applied off the critical chain). Logits are
// prefetched in ping-pong batches of 8 (one vmcnt wait per 8 steps).
__global__ __launch_bounds__(128, 1)
void crf_nll_kernel(const float* __restrict__ logits,
                    const float* __restrict__ Tm,
                    const int* __restrict__ labels,
                    const int* __restrict__ mask_g,
                    float* __restrict__ out,
                    int B, int S)
{
    const int b   = blockIdx.x;
    const int tid = threadIdx.x;
    const int w   = tid >> 6;          // 0 = forward, 1 = backward
    const int j   = tid & 63;
    constexpr int L = 66, START = 64, END = 65;

    __shared__ __align__(16) float exch[64];
    __shared__ int   redI[2];
    __shared__ float redF[2];
    __shared__ int   redM;

    const float* lg  = logits + (size_t)b * S * 64;
    const int*   lab = labels + (size_t)b * S;
    const int*   msk = mask_g + (size_t)b * S;

    // ---------- prephase: len + full gold score (unary gather + transitions)
    int   lensum = 0;
    float gsum   = 0.0f;
    for (int t0 = tid; t0 < S; t0 += 128) {
        if (msk[t0]) {
            ++lensum;
            int lc = lab[t0];
            float ga = lg[(size_t)t0 * 64 + lc];
            if (t0 > 0) ga += Tm[lc * L + lab[t0 - 1]];
            gsum += ga;
        }
    }
    #pragma unroll
    for (int off = 32; off; off >>= 1) {
        lensum += __shfl_xor(lensum, off);
        gsum   += __shfl_xor(gsum, off);
    }
    if (j == 0) { redI[w] = lensum; redF[w] = gsum; }

    // ---------- expT row/col for this lane (fwd: row j; bwd: column j)
    float eT[64];
    if (w == 0) {
        #pragma unroll
        for (int k = 0; k < 64; ++k)
            eT[k] = __builtin_amdgcn_exp2f(Tm[j * L + k] * LOG2E);
    } else {
        #pragma unroll
        for (int k = 0; k < 64; ++k)
            eT[k] = __builtin_amdgcn_exp2f(Tm[k * L + j] * LOG2E);
    }

    __syncthreads();
    const int   len   = redI[0] + redI[1];
    const float goldp = redF[0] + redF[1];
    const int   m_mid = (len + 1) >> 1;

    float u;
    int   M2i   = 0;        // exact log2-scale accumulator (uniform -> SGPR)
    int   epend = 0;        // pending exponent (matches rprev)
    float rprev = 1.0f;     // reciprocal of previous step's power-of-two scale

    auto STEP = [&](float lv, bool useEl) {
        float el  = useEl ? __builtin_amdgcn_exp2f(lv * LOG2E) : 1.0f;
        float fac = el * rprev;                         // off-chain
        const unsigned uu = __float_as_uint(u);
        float s0 = 0.f, s1 = 0.f, s2 = 0.f, s3 = 0.f;
        #pragma unroll
        for (int r = 0; r < 16; ++r) {
            float p0 = __uint_as_float(__builtin_amdgcn_readlane(uu, 4*r + 0));
            float p1 = __uint_as_float(__builtin_amdgcn_readlane(uu, 4*r + 1));
            float p2 = __uint_as_float(__builtin_amdgcn_readlane(uu, 4*r + 2));
            float p3 = __uint_as_float(__builtin_amdgcn_readlane(uu, 4*r + 3));
            s0 = fmaf(p0, eT[4*r + 0], s0);
            s1 = fmaf(p1, eT[4*r + 1], s1);
            s2 = fmaf(p2, eT[4*r + 2], s2);
            s3 = fmaf(p3, eT[4*r + 3], s3);
        }
        float Sv = (s0 + s1) + (s2 + s3);
        u = Sv * fac;                                   // apply prev scale + logit
        M2i += epend;                                   // SALU, exact
        unsigned E = __builtin_amdgcn_readfirstlane(__float_as_uint(Sv)) >> 23;
        rprev = __uint_as_float((254u - E) << 23);      // 2^-(E-127), exact
        epend = (int)E - 127;
    };

    if (w == 0) {
        // ---------------- forward: A_1 init, then steps t = 1 .. tmax
        const int tmax = m_mid - 1;
        u = __builtin_amdgcn_exp2f((lg[j] + Tm[j * L + START]) * LOG2E);
        auto ldf = [&](int t) {
            t = (t > tmax) ? tmax : t; t = (t < 1) ? 1 : t;
            return lg[(size_t)t * 64 + j];
        };
        float La[8], Lb[8];
        #pragma unroll
        for (int q = 0; q < 8; ++q) La[q] = ldf(1 + q);
        int base = 1;
        for (; base + 15 <= tmax; base += 16) {
            #pragma unroll
            for (int q = 0; q < 8; ++q) Lb[q] = ldf(base + 8 + q);
            #pragma unroll
            for (int q = 0; q < 8; ++q) STEP(La[q], true);
            #pragma unroll
            for (int q = 0; q < 8; ++q) La[q] = ldf(base + 16 + q);
            #pragma unroll
            for (int q = 0; q < 8; ++q) STEP(Lb[q], true);
        }
        int rem = tmax - base + 1;                      // 0..15
        if (rem >= 8) {
            #pragma unroll
            for (int q = 0; q < 8; ++q) Lb[q] = ldf(base + 8 + q);
            #pragma unroll
            for (int q = 0; q < 8; ++q) STEP(La[q], true);
            base += 8; rem -= 8;
            #pragma unroll
            for (int q = 0; q < 8; ++q) { if (q < rem) STEP(Lb[q], true); }
        } else {
            #pragma unroll
            for (int q = 0; q < 8; ++q) { if (q < rem) STEP(La[q], true); }
        }
    } else {
        // ---------------- backward: B_len init (+ logit_{len-1}), n_b steps
        const int n_b = len - m_mid;
        float initl = (n_b > 0) ? lg[(size_t)(len - 1) * 64 + j] : 0.0f;
        u = __builtin_amdgcn_exp2f((Tm[END * L + j] + initl) * LOG2E);
        auto ldb = [&](int i) {
            int idx = len - 2 - i; idx = (idx < 0) ? 0 : idx;
            return lg[(size_t)idx * 64 + j];
        };
        float La[8], Lb[8];
        #pragma unroll
        for (int q = 0; q < 8; ++q) La[q] = ldb(q);
        int base = 0;
        for (; base + 15 <= n_b - 1; base += 16) {
            #pragma unroll
            for (int q = 0; q < 8; ++q) Lb[q] = ldb(base + 8 + q);
            #pragma unroll
            for (int q = 0; q < 8; ++q) STEP(La[q], base + q < n_b - 1);
            #pragma unroll
            for (int q = 0; q < 8; ++q) La[q] = ldb(base + 16 + q);
            #pragma unroll
            for (int q = 0; q < 8; ++q) STEP(Lb[q], base + 8 + q < n_b - 1);
        }
        int rem = n_b - base;                           // 0..15
        if (rem >= 8) {
            #pragma unroll
            for (int q = 0; q < 8; ++q) Lb[q] = ldb(base + 8 + q);
            #pragma unroll
            for (int q = 0; q < 8; ++q) STEP(La[q], base + q < n_b - 1);
            base += 8; rem -= 8;
            #pragma unroll
            for (int q = 0; q < 8; ++q) { if (q < rem) STEP(Lb[q], base + q < n_b - 1); }
        } else {
            #pragma unroll
            for (int q = 0; q < 8; ++q) { if (q < rem) STEP(La[q], base + q < n_b - 1); }
        }
    }

    // ---------- combine: Z = ln2 * (M2f + M2b + log2( sum_k uf[k]*ub[k] ))
    if (w == 1) {
        exch[j] = u;
        if (j == 0) redM = M2i;
    }
    __syncthreads();
    if (w == 0) {
        float v = u * exch[j];
        #pragma unroll
        for (int off = 32; off; off >>= 1) v += __shfl_xor(v, off);
        if (j == 0) {
            int    Msum = M2i + redM;
            double Z    = ((double)Msum + (double)__builtin_amdgcn_logf(v)) * LN2;
            int lab0 = lab[0];
            int labl = lab[len - 1];
            float goldall = goldp + Tm[lab0 * L + START] + Tm[END * L + labl];
            out[b] = (float)(Z - (double)goldall);
        }
    }
}

extern "C" void kernel_launch(void* const* d_in, const int* in_sizes, int n_in,
                              void* d_out, int out_size, void* d_ws, size_t ws_size,
                              hipStream_t stream) {
    const float* logits = (const float*)d_in[0];
    const float* Tm     = (const float*)d_in[1];
    const int*   labels = (const int*)d_in[2];
    const int*   mask   = (const int*)d_in[3];
    float*       out    = (float*)d_out;

    const int B = out_size;                 // 512
    const int S = in_sizes[2] / B;          // 1024

    crf_nll_kernel<<<dim3(B), dim3(128), 0, stream>>>(logits, Tm, labels, mask, out, B, S);
}